// Round 10
// baseline (8787.138 us; speedup 1.0000x reference)
//
#include <hip/hip_runtime.h>
#include <hip/hip_bf16.h>

#define N2   2048
#define CH   256
#define FFNC 1024

typedef unsigned short ushort_t;
typedef unsigned int   uint_t;

// ---------------- workspace layout (float offsets), total 40.5MB ----------------
#define OFF_QB     0u                        // bf16 Q [2][2048][2048] = 4M float slots
#define OFF_IMFT   4194304u                  // [2][2048][256] f32
#define OFF_CPART0 5242880u                  // [2][512][2048] ping  ; WiT pre-ipot, att after
#define OFF_CPART1 7340032u                  // [2][512][2048] pong
#define OFF_PCLS   9437184u
#define OFF_ICLS   9441280u
#define OFF_BVEC   9445376u
#define OFF_AVEC   9449472u
#define OFF_FLAG   9453568u                  // uint flag (+pad)
#define OFF_WOUTT  9457664u                  // [512][256]
#define OFF_WF1T   9588736u                  // [256][1024]
#define OFF_WF2T   9850880u                  // [1024][256]  end = 10113024 floats

// ---------------- bf16 helpers ----------------
__device__ __forceinline__ float bf2f(uint_t u) {
    return __uint_as_float(u << 16);
}
__device__ __forceinline__ ushort_t f2bf(float f) {
    __hip_bfloat16 h = __float2bfloat16(f);   // RNE
    ushort_t u;
    __builtin_memcpy(&u, &h, 2);
    return u;
}

__device__ __forceinline__ void blockReduce2(float& x, float& y, float* sred) {
    #pragma unroll
    for (int off = 32; off; off >>= 1) {
        x += __shfl_xor(x, off);
        y += __shfl_xor(y, off);
    }
    const int wave = threadIdx.x >> 6, lane = threadIdx.x & 63;
    if (lane == 0) { sred[wave] = x; sred[4 + wave] = y; }
    __syncthreads();
    x = sred[0] + sred[1] + sred[2] + sred[3];
    y = sred[4] + sred[5] + sred[6] + sred[7];
    __syncthreads();
}

// ---------------- tiny prep kernels ----------------
__global__ void __launch_bounds__(256) cls_max_k(
    const float* __restrict__ pc, const float* __restrict__ ic,
    float* __restrict__ pcls, float* __restrict__ icls) {
    const int g = blockIdx.x * 256 + threadIdx.x;  // 4096
    const int b = g >> 11, n = g & 2047;
    float m1 = -1e30f, m2 = -1e30f;
    #pragma unroll
    for (int k = 0; k < 10; ++k) {
        const float v1 = pc[((size_t)b * 10 + k) * N2 + n];
        const float v2 = ic[((size_t)b * 10 + k) * N2 + n];
        m1 = fmaxf(m1, 1.f / (1.f + __expf(-v1)));
        m2 = fmaxf(m2, 1.f / (1.f + __expf(-v2)));
    }
    pcls[g] = m1; icls[g] = m2;
}

__global__ void __launch_bounds__(256) transpose_k(
    const float* __restrict__ in, float* __restrict__ out, int R, int C) {
    __shared__ float t[32][33];
    const int nct = C >> 5;
    const int bx = blockIdx.x % nct, by = blockIdx.x / nct;
    const int c0 = bx * 32, r0 = by * 32;
    const int tx = threadIdx.x & 31, ty = threadIdx.x >> 5;
    #pragma unroll
    for (int i = 0; i < 4; ++i) {
        const int r = ty + i * 8;
        t[r][tx] = in[(size_t)(r0 + r) * C + c0 + tx];
    }
    __syncthreads();
    #pragma unroll
    for (int i = 0; i < 4; ++i) {
        const int r = ty + i * 8;
        out[(size_t)(c0 + r) * R + r0 + tx] = t[tx][r];
    }
}

// proj + pos-embed
__global__ void __launch_bounds__(256) proj_rows(
    const float* __restrict__ F, const float* __restrict__ WT,
    const float* __restrict__ bias, const float* __restrict__ Wpos,
    const float* __restrict__ bpos, const float* __restrict__ pos,
    float* __restrict__ outb) {
    const int b = blockIdx.x >> 8;
    const int n0 = (blockIdx.x & 255) * 8;
    const int tid = threadIdx.x;
    __shared__ float s_x[8][256];
    for (int idx = tid; idx < 2048; idx += 256) {
        const int r = idx & 7, c = idx >> 3;
        s_x[r][c] = F[((size_t)b * CH + c) * N2 + n0 + r];
    }
    __syncthreads();
    float acc[8] = {0, 0, 0, 0, 0, 0, 0, 0};
    for (int c = 0; c < 256; ++c) {
        const float w = WT[(size_t)c * CH + tid];
        #pragma unroll
        for (int r = 0; r < 8; ++r) acc[r] += s_x[r][c] * w;
    }
    const float badd = bias[tid] + bpos[tid];
    const float w0 = Wpos[tid * 2 + 0], w1 = Wpos[tid * 2 + 1];
    #pragma unroll
    for (int r = 0; r < 8; ++r) {
        const int n = n0 + r;
        const float p0 = pos[((size_t)b * N2 + n) * 2 + 0];
        const float p1 = pos[((size_t)b * N2 + n) * 2 + 1];
        outb[((size_t)b * N2 + n) * CH + tid] = acc[r] + badd + w0 * p0 + w1 * p1;
    }
}

// ---------------- IPOT (bf16 Q, 4 rows/block, grid 1024, fused reduce) ----------------
// Thread t owns contiguous cols {8t..8t+7}: one uint4 (8 bf16) per row.

__device__ __forceinline__ void load_cols8(const float* ipos, int batch, int tid,
                                           float* ixr, float* iyr) {
    const float4* ip4 = (const float4*)(ipos + (size_t)batch * (N2 * 2));
    #pragma unroll
    for (int m = 0; m < 4; ++m) {
        const float4 v = ip4[4 * tid + m];
        ixr[2 * m + 0] = v.x; iyr[2 * m + 0] = v.y;
        ixr[2 * m + 1] = v.z; iyr[2 * m + 1] = v.w;
    }
}

__device__ __forceinline__ void unpack8(const uint4 v, float* q) {
    q[0] = bf2f(v.x & 0xffffu); q[1] = bf2f(v.x >> 16);
    q[2] = bf2f(v.y & 0xffffu); q[3] = bf2f(v.y >> 16);
    q[4] = bf2f(v.z & 0xffffu); q[5] = bf2f(v.z >> 16);
    q[6] = bf2f(v.w & 0xffffu); q[7] = bf2f(v.w >> 16);
}

__device__ __forceinline__ uint4 pack8(const float* q) {
    uint4 v;
    v.x = (uint_t)f2bf(q[0]) | ((uint_t)f2bf(q[1]) << 16);
    v.y = (uint_t)f2bf(q[2]) | ((uint_t)f2bf(q[3]) << 16);
    v.z = (uint_t)f2bf(q[4]) | ((uint_t)f2bf(q[5]) << 16);
    v.w = (uint_t)f2bf(q[6]) | ((uint_t)f2bf(q[7]) << 16);
    return v;
}

// init: Q1 = max(G,1e-6) (bf16-rounded); a1 -> avec; cs -> cpartW; zero flag
__global__ void __launch_bounds__(256, 4) ipot_init_k(
    ushort_t* __restrict__ Q, const float* __restrict__ ppos, const float* __restrict__ ipos,
    const float* __restrict__ pcls, float* __restrict__ avec, float* __restrict__ cpartW,
    uint_t* __restrict__ flag) {
    const int blk = blockIdx.x;
    const int batch = blk >> 9;
    const int p = blk & 511;
    const int r0 = p * 4;
    const int tid = threadIdx.x, wave = tid >> 6, lane = tid & 63;
    __shared__ float s_tot[4][4];

    if (blk == 0 && tid == 0)
        __hip_atomic_store(flag, 0u, __ATOMIC_RELAXED, __HIP_MEMORY_SCOPE_AGENT);

    float ixr[8], iyr[8];
    load_cols8(ipos, batch, tid, ixr, iyr);
    float px[4], py[4], pcl4[4];
    #pragma unroll
    for (int j = 0; j < 4; ++j) {
        px[j] = ppos[((size_t)batch * N2 + r0 + j) * 2 + 0];
        py[j] = ppos[((size_t)batch * N2 + r0 + j) * 2 + 1];
        pcl4[j] = pcls[batch * N2 + r0 + j];
    }
    ushort_t* Qb = Q + (size_t)batch * N2 * N2;
    float cs[8] = {0, 0, 0, 0, 0, 0, 0, 0};

    float qn[4][8];
    float rd[4];
    #pragma unroll
    for (int jj = 0; jj < 4; ++jj) {
        rd[jj] = 0.f;
        #pragma unroll
        for (int k = 0; k < 8; ++k) {
            const float dx = px[jj] - ixr[k], dy = py[jj] - iyr[k];
            const float v = fmaxf(__expf(-0.1f * sqrtf(dx * dx + dy * dy)), 1e-6f);
            qn[jj][k] = bf2f(f2bf(v));       // self-consistent rounded value
            rd[jj] += qn[jj][k];
        }
        ((uint4*)(Qb + (size_t)(r0 + jj) * N2))[tid] = pack8(qn[jj]);
    }
    #pragma unroll
    for (int off = 32; off; off >>= 1) {
        #pragma unroll
        for (int jj = 0; jj < 4; ++jj) rd[jj] += __shfl_xor(rd[jj], off);
    }
    if (lane == 0) {
        #pragma unroll
        for (int jj = 0; jj < 4; ++jj) s_tot[wave][jj] = rd[jj];
    }
    __syncthreads();
    #pragma unroll
    for (int jj = 0; jj < 4; ++jj) {
        const float tot = s_tot[0][jj] + s_tot[1][jj] + s_tot[2][jj] + s_tot[3][jj];
        const float a = pcl4[jj] / (tot * (1.f / 2048.f) + 1e-6f);
        if (tid == 0) avec[batch * N2 + r0 + jj] = a;
        #pragma unroll
        for (int k = 0; k < 8; ++k) cs[k] += a * qn[jj][k];
    }
    float4* cp4 = (float4*)(cpartW + ((size_t)batch * 512 + p) * N2);
    float4 l, h4;
    l.x = cs[0]; l.y = cs[1]; l.z = cs[2]; l.w = cs[3];
    h4.x = cs[4]; h4.y = cs[5]; h4.z = cs[6]; h4.w = cs[7];
    cp4[2 * tid] = l; cp4[2 * tid + 1] = h4;
}

// standalone reduce (used once before fin): bvec = icls/(colsum cpart + 1e-6)
__global__ void __launch_bounds__(256) ipot_red_k(
    const float* __restrict__ cpart, const float* __restrict__ icls,
    float* __restrict__ bvec) {
    const int b = blockIdx.x >> 5;
    const int c0 = (blockIdx.x & 31) * 64;
    const int tid = threadIdx.x;
    const int c = tid & 63, pg = tid >> 6;
    __shared__ float s_part[4][64];
    const float* cpb = cpart + (size_t)b * 512 * N2 + c0 + c;
    float s = 0.f;
    #pragma unroll 8
    for (int k = 0; k < 128; ++k) s += cpb[(size_t)(pg + 4 * k) * N2];
    s_part[pg][c] = s;
    __syncthreads();
    if (tid < 64) {
        const float tot = s_part[0][tid] + s_part[1][tid] + s_part[2][tid] + s_part[3][tid];
        bvec[b * N2 + c0 + tid] = icls[b * N2 + c0 + tid] / (tot + 1e-6f);
    }
}

// fused iteration: [blk<256: reduce cpartR -> bvec, bump flag] ; all: w=G*a*q,
// wait flag (fallback: direct colsum), Q <- max(w*b,1e-6) bf16; a'; cs -> cpartW
__global__ void __launch_bounds__(256, 4) ipot_ur_k(
    ushort_t* __restrict__ Q, const float* __restrict__ ppos, const float* __restrict__ ipos,
    const float* __restrict__ pcls, const float* __restrict__ icls,
    float* __restrict__ avec, const float* __restrict__ cpartR,
    float* __restrict__ cpartW, float* __restrict__ bvec,
    uint_t* __restrict__ flag, int t) {
    const int blk = blockIdx.x;
    const int batch = blk >> 9;
    const int p = blk & 511;
    const int r0 = p * 4;
    const int tid = threadIdx.x, wave = tid >> 6, lane = tid & 63;
    __shared__ float s_tot[4][4];
    __shared__ float s_red[16][17];
    __shared__ int s_fb;

    // ---- producer phase: blocks 0..255 build bvec from cpartR
    if (blk < 256) {
        const int pb = blk >> 7;             // producer batch
        const int c0 = (blk & 127) * 16;
        const int cl = tid & 15, pg = tid >> 4;
        const float* cpb = cpartR + (size_t)pb * 512 * N2 + c0 + cl;
        float s = 0.f;
        #pragma unroll 8
        for (int k = 0; k < 32; ++k) s += cpb[(size_t)(pg + 16 * k) * N2];
        s_red[pg][cl] = s;
        __syncthreads();
        if (tid < 16) {
            float tot = 0.f;
            #pragma unroll
            for (int g2 = 0; g2 < 16; ++g2) tot += s_red[g2][tid];
            const float bv = icls[pb * N2 + c0 + tid] / (tot + 1e-6f);
            __hip_atomic_store(&bvec[pb * N2 + c0 + tid], bv,
                               __ATOMIC_RELAXED, __HIP_MEMORY_SCOPE_AGENT);
        }
        __syncthreads();
        if (tid == 0) {
            __threadfence();
            __hip_atomic_fetch_add(flag, 1u, __ATOMIC_RELEASE, __HIP_MEMORY_SCOPE_AGENT);
        }
    }

    // ---- heavy precompute (no b needed): w = G * a * q
    float ixr[8], iyr[8];
    load_cols8(ipos, batch, tid, ixr, iyr);
    float px[4], py[4], pcl4[4], a_cur[4];
    #pragma unroll
    for (int j = 0; j < 4; ++j) {
        px[j] = ppos[((size_t)batch * N2 + r0 + j) * 2 + 0];
        py[j] = ppos[((size_t)batch * N2 + r0 + j) * 2 + 1];
        pcl4[j] = pcls[batch * N2 + r0 + j];
        a_cur[j] = avec[batch * N2 + r0 + j];
    }
    ushort_t* Qb = Q + (size_t)batch * N2 * N2;
    float w[4][8];
    #pragma unroll
    for (int jj = 0; jj < 4; ++jj) {
        float qv[8];
        unpack8(((const uint4*)(Qb + (size_t)(r0 + jj) * N2))[tid], qv);
        const float a = a_cur[jj];
        #pragma unroll
        for (int k = 0; k < 8; ++k) {
            const float dx = px[jj] - ixr[k], dy = py[jj] - iyr[k];
            const float G = __expf(-0.1f * sqrtf(dx * dx + dy * dy));
            w[jj][k] = G * (a * qv[k]);
        }
    }

    // ---- wait for bvec (spin with timeout fallback)
    if (tid == 0) {
        s_fb = 0;
        const uint_t target = 256u * (uint_t)t;
        int spins = 0;
        while (__hip_atomic_load(flag, __ATOMIC_ACQUIRE, __HIP_MEMORY_SCOPE_AGENT) < target) {
            __builtin_amdgcn_s_sleep(8);
            if (++spins > 50000) { s_fb = 1; break; }
        }
    }
    __syncthreads();

    float bb[8];
    if (s_fb) {
        // fallback: compute my 8 cols' sums directly from cpartR (correct, slow)
        #pragma unroll
        for (int k = 0; k < 8; ++k) {
            const int col = 8 * tid + k;
            float s = 0.f;
            for (int pp = 0; pp < 512; ++pp)
                s += cpartR[(size_t)batch * 512 * N2 + (size_t)pp * N2 + col];
            bb[k] = icls[batch * N2 + col] / (s + 1e-6f);
        }
    } else {
        const float* bvb = bvec + (size_t)batch * N2 + 8 * tid;
        #pragma unroll
        for (int k = 0; k < 8; ++k)
            bb[k] = __hip_atomic_load(&bvb[k], __ATOMIC_RELAXED, __HIP_MEMORY_SCOPE_AGENT);
    }

    // ---- finish: Q' = max(w*b,1e-6) bf16; rowdot -> a'; cs = a' * Q'
    float cs[8] = {0, 0, 0, 0, 0, 0, 0, 0};
    float qn[4][8];
    float rd[4];
    #pragma unroll
    for (int jj = 0; jj < 4; ++jj) {
        rd[jj] = 0.f;
        #pragma unroll
        for (int k = 0; k < 8; ++k) {
            const float v = fmaxf(w[jj][k] * bb[k], 1e-6f);
            qn[jj][k] = bf2f(f2bf(v));       // rounded value actually stored
            rd[jj] += qn[jj][k] * bb[k];
        }
        ((uint4*)(Qb + (size_t)(r0 + jj) * N2))[tid] = pack8(qn[jj]);
    }
    #pragma unroll
    for (int off = 32; off; off >>= 1) {
        #pragma unroll
        for (int jj = 0; jj < 4; ++jj) rd[jj] += __shfl_xor(rd[jj], off);
    }
    if (lane == 0) {
        #pragma unroll
        for (int jj = 0; jj < 4; ++jj) s_tot[wave][jj] = rd[jj];
    }
    __syncthreads();
    #pragma unroll
    for (int jj = 0; jj < 4; ++jj) {
        const float tot = s_tot[0][jj] + s_tot[1][jj] + s_tot[2][jj] + s_tot[3][jj];
        const float a = pcl4[jj] / (tot + 1e-6f);
        if (tid == 0) avec[batch * N2 + r0 + jj] = a;
        #pragma unroll
        for (int k = 0; k < 8; ++k) cs[k] += a * qn[jj][k];
    }
    float4* cp4 = (float4*)(cpartW + ((size_t)batch * 512 + p) * N2);
    float4 l, h4;
    l.x = cs[0]; l.y = cs[1]; l.z = cs[2]; l.w = cs[3];
    h4.x = cs[4]; h4.y = cs[5]; h4.z = cs[6]; h4.w = cs[7];
    cp4[2 * tid] = l; cp4[2 * tid + 1] = h4;
}

// final: res = a*Q*b, row-L1-normalize, write into Q (bf16)
__global__ void __launch_bounds__(256, 4) ipot_fin_k(
    ushort_t* __restrict__ Q, const float* __restrict__ pcls,
    const float* __restrict__ bvec, const float* __restrict__ avec) {
    const int blk = blockIdx.x;
    const int batch = blk >> 9;
    const int p = blk & 511;
    const int r0 = p * 4;
    const int tid = threadIdx.x, wave = tid >> 6, lane = tid & 63;
    __shared__ float s_tot[4][4];

    float bb[8];
    {
        const float4* bv4 = (const float4*)(bvec + (size_t)batch * N2);
        const float4 l = bv4[2 * tid], h4 = bv4[2 * tid + 1];
        bb[0] = l.x; bb[1] = l.y; bb[2] = l.z; bb[3] = l.w;
        bb[4] = h4.x; bb[5] = h4.y; bb[6] = h4.z; bb[7] = h4.w;
    }
    float a4[4];
    #pragma unroll
    for (int j = 0; j < 4; ++j) a4[j] = avec[batch * N2 + r0 + j];
    ushort_t* Qb = Q + (size_t)batch * N2 * N2;

    float vv[4][8];
    float rs[4];
    #pragma unroll
    for (int jj = 0; jj < 4; ++jj) {
        float qv[8];
        unpack8(((const uint4*)(Qb + (size_t)(r0 + jj) * N2))[tid], qv);
        rs[jj] = 0.f;
        const float a = a4[jj];
        #pragma unroll
        for (int k = 0; k < 8; ++k) {
            const float v = (a * qv[k]) * bb[k];
            vv[jj][k] = v;
            rs[jj] += v;
        }
    }
    #pragma unroll
    for (int off = 32; off; off >>= 1) {
        #pragma unroll
        for (int jj = 0; jj < 4; ++jj) rs[jj] += __shfl_xor(rs[jj], off);
    }
    if (lane == 0) {
        #pragma unroll
        for (int jj = 0; jj < 4; ++jj) s_tot[wave][jj] = rs[jj];
    }
    __syncthreads();
    #pragma unroll
    for (int jj = 0; jj < 4; ++jj) {
        const float tot = s_tot[0][jj] + s_tot[1][jj] + s_tot[2][jj] + s_tot[3][jj];
        const float sc = 1.f / fmaxf(tot, 1e-12f);
        float o[8];
        #pragma unroll
        for (int k = 0; k < 8; ++k) o[k] = vv[jj][k] * sc;
        ((uint4*)(Qb + (size_t)(r0 + jj) * N2))[tid] = pack8(o);
    }
}

// ---------------- att GEMM ----------------
__global__ void __launch_bounds__(256) att_zero_k(float* __restrict__ att) {
    const int idx = blockIdx.x * 256 + threadIdx.x;
    float4 z; z.x = 0.f; z.y = 0.f; z.z = 0.f; z.w = 0.f;
    ((float4*)att)[idx] = z;
}

__global__ void __launch_bounds__(256, 4) att_gemm(
    const ushort_t* __restrict__ R, const float* __restrict__ V, float* __restrict__ att) {
    const int bid = blockIdx.x;
    const int nt = bid & 31, ct = (bid >> 5) & 3, ks = (bid >> 7) & 3, b = bid >> 9;
    const int n0 = nt * 64, c0 = ct * 64, k00 = ks * 512;
    __shared__ float sRT[16][68];
    __shared__ float sV[16][68];
    const int tid = threadIdx.x;
    const int ny = tid & 15, cx = tid >> 4;
    float acc[4][4] = {};
    const ushort_t* Rb = R + (size_t)b * N2 * N2;
    const float* Vb = V + (size_t)b * N2 * CH;
    const int snl = tid & 63, skk0 = (tid >> 6) * 4;
    for (int k0 = k00; k0 < k00 + 512; k0 += 16) {
        {
            const uint2 v = *(const uint2*)&Rb[(size_t)(n0 + snl) * N2 + k0 + skk0];
            sRT[skk0 + 0][snl] = bf2f(v.x & 0xffffu);
            sRT[skk0 + 1][snl] = bf2f(v.x >> 16);
            sRT[skk0 + 2][snl] = bf2f(v.y & 0xffffu);
            sRT[skk0 + 3][snl] = bf2f(v.y >> 16);
        }
        for (int idx = tid; idx < 1024; idx += 256) {
            const int kk = idx >> 6, cl = idx & 63;
            sV[kk][cl] = Vb[(size_t)(k0 + kk) * CH + c0 + cl];
        }
        __syncthreads();
        #pragma unroll
        for (int kk = 0; kk < 16; ++kk) {
            const float4 av = *(const float4*)&sRT[kk][4 * ny];
            const float4 bv = *(const float4*)&sV[kk][4 * cx];
            acc[0][0] += av.x * bv.x; acc[0][1] += av.x * bv.y; acc[0][2] += av.x * bv.z; acc[0][3] += av.x * bv.w;
            acc[1][0] += av.y * bv.x; acc[1][1] += av.y * bv.y; acc[1][2] += av.y * bv.z; acc[1][3] += av.y * bv.w;
            acc[2][0] += av.z * bv.x; acc[2][1] += av.z * bv.y; acc[2][2] += av.z * bv.z; acc[2][3] += av.z * bv.w;
            acc[3][0] += av.w * bv.x; acc[3][1] += av.w * bv.y; acc[3][2] += av.w * bv.z; acc[3][3] += av.w * bv.w;
        }
        __syncthreads();
    }
    #pragma unroll
    for (int i = 0; i < 4; ++i)
        #pragma unroll
        for (int j = 0; j < 4; ++j)
            atomicAdd(&att[((size_t)b * N2 + n0 + 4 * ny + i) * CH + c0 + 4 * cx + j], acc[i][j]);
}

// ---------------- out_projection + LN ----------------
__global__ void __launch_bounds__(256) outproj_k(
    const float* __restrict__ pf, const float* __restrict__ att,
    const float* __restrict__ WoutT,
    const float* __restrict__ bout, const float* __restrict__ g,
    const float* __restrict__ be, float* __restrict__ y) {
    const int b = blockIdx.x >> 8;
    const int n0 = (blockIdx.x & 255) * 8;
    const int tid = threadIdx.x;
    __shared__ float s_x[8][512];
    __shared__ float sred[8];
    for (int idx = tid; idx < 2048; idx += 256) {
        const int k = idx & 255, r = idx >> 8;
        s_x[r][k] = pf[((size_t)b * N2 + n0 + r) * CH + k];
        s_x[r][256 + k] = att[((size_t)b * N2 + n0 + r) * CH + k];
    }
    __syncthreads();
    float acc[8] = {0, 0, 0, 0, 0, 0, 0, 0};
    for (int k = 0; k < 512; ++k) {
        const float w = WoutT[(size_t)k * CH + tid];
        #pragma unroll
        for (int r = 0; r < 8; ++r) acc[r] += s_x[r][k] * w;
    }
    const float bo = bout[tid], gg = g[tid], bb = be[tid];
    #pragma unroll
    for (int r = 0; r < 8; ++r) {
        const float v = acc[r] + bo;
        float s1 = v, s2 = v * v;
        blockReduce2(s1, s2, sred);
        const float mu = s1 * (1.f / 256.f);
        const float var = s2 * (1.f / 256.f) - mu * mu;
        y[((size_t)b * N2 + n0 + r) * CH + tid] = (v - mu) * rsqrtf(var + 1e-5f) * gg + bb;
    }
}

// ---------------- fused FFN + residual + LN + pred head ----------------
__global__ void __launch_bounds__(256) ffn_k(
    const float* __restrict__ y, const float* __restrict__ Wf1T,
    const float* __restrict__ bf1, const float* __restrict__ Wf2T,
    const float* __restrict__ bf2, const float* __restrict__ gln,
    const float* __restrict__ bln, const float* __restrict__ Wpred,
    const float* __restrict__ bpred, const float* __restrict__ pos,
    float* __restrict__ y2, float* __restrict__ out1,
    float* __restrict__ out2) {
    const int b = blockIdx.x >> 8;
    const int n0 = (blockIdx.x & 255) * 8;
    const int tid = threadIdx.x;
    __shared__ float s_y[8][256];
    __shared__ float s_h[8][1024];
    __shared__ float sred[8];
    for (int idx = tid; idx < 2048; idx += 256) {
        const int c = idx & 255, r = idx >> 8;
        s_y[r][c] = y[((size_t)b * N2 + n0 + r) * CH + c];
    }
    __syncthreads();
    float acc[4][8] = {};
    for (int c = 0; c < 256; ++c) {
        float yv[8];
        #pragma unroll
        for (int r = 0; r < 8; ++r) yv[r] = s_y[r][c];
        #pragma unroll
        for (int fi = 0; fi < 4; ++fi) {
            const float w = Wf1T[(size_t)c * FFNC + fi * 256 + tid];
            #pragma unroll
            for (int r = 0; r < 8; ++r) acc[fi][r] += yv[r] * w;
        }
    }
    #pragma unroll
    for (int fi = 0; fi < 4; ++fi) {
        const int f = fi * 256 + tid;
        const float bb = bf1[f];
        #pragma unroll
        for (int r = 0; r < 8; ++r) s_h[r][f] = fmaxf(acc[fi][r] + bb, 0.f);
    }
    __syncthreads();
    float a2[8] = {0, 0, 0, 0, 0, 0, 0, 0};
    for (int f = 0; f < 1024; ++f) {
        const float w = Wf2T[(size_t)f * CH + tid];
        #pragma unroll
        for (int r = 0; r < 8; ++r) a2[r] += s_h[r][f] * w;
    }
    const float bfv = bf2[tid], gg = gln[tid], bb2 = bln[tid];
    const float wp0 = Wpred[tid], wp1 = Wpred[CH + tid];
    #pragma unroll
    for (int r = 0; r < 8; ++r) {
        const int n = n0 + r;
        const float v = a2[r] + bfv + s_y[r][tid];
        float s1 = v, s2 = v * v;
        blockReduce2(s1, s2, sred);
        const float mu = s1 * (1.f / 256.f);
        const float var = s2 * (1.f / 256.f) - mu * mu;
        const float xo = (v - mu) * rsqrtf(var + 1e-5f) * gg + bb2;
        y2[((size_t)b * N2 + n) * CH + tid] = xo;
        float d0 = wp0 * xo, d1 = wp1 * xo;
        blockReduce2(d0, d1, sred);
        if (tid == 0) {
            const float c0v = d0 + bpred[0] + pos[((size_t)b * N2 + n) * 2 + 0];
            const float c1v = d1 + bpred[1] + pos[((size_t)b * N2 + n) * 2 + 1];
            out2[((size_t)b * 2 + 0) * N2 + n] = c0v;
            out2[((size_t)b * 2 + 1) * N2 + n] = c1v;
            out1[((size_t)b * N2 + n) * 2 + 0] = c0v;
            out1[((size_t)b * N2 + n) * 2 + 1] = c1v;
        }
    }
}

// ---------------- transpose xo -> out0 [b][c][n] f32 ----------------
__global__ void __launch_bounds__(256) out_x_k(
    const float* __restrict__ y2, float* __restrict__ out0) {
    __shared__ float t[32][33];
    const int bid = blockIdx.x;                      // 2*64*8 = 1024
    const int ct = bid & 7, nt = (bid >> 3) & 63, b = bid >> 9;
    const int tx = threadIdx.x & 31, ty = threadIdx.x >> 5;
    #pragma unroll
    for (int i = 0; i < 4; ++i) {
        const int r = ty + i * 8;
        t[r][tx] = y2[((size_t)b * N2 + nt * 32 + r) * CH + ct * 32 + tx];
    }
    __syncthreads();
    #pragma unroll
    for (int i = 0; i < 4; ++i) {
        const int r = ty + i * 8;
        out0[((size_t)b * CH + ct * 32 + r) * N2 + nt * 32 + tx] = t[tx][r];
    }
}

// ---------------- launcher ----------------
extern "C" void kernel_launch(void* const* d_in, const int* in_sizes, int n_in,
                              void* d_out, int out_size, void* d_ws, size_t ws_size,
                              hipStream_t stream) {
    const float* ptsf  = (const float*)d_in[0];
    const float* ppos  = (const float*)d_in[1];
    const float* imgf  = (const float*)d_in[2];
    const float* ipos  = (const float*)d_in[3];
    const float* pcin  = (const float*)d_in[4];
    const float* icin  = (const float*)d_in[5];
    const float* Wp    = (const float*)d_in[6];
    const float* bp    = (const float*)d_in[7];
    const float* Wi    = (const float*)d_in[8];
    const float* bi    = (const float*)d_in[9];
    const float* Wqp   = (const float*)d_in[10];
    const float* bqp   = (const float*)d_in[11];
    const float* Wkp   = (const float*)d_in[12];
    const float* bkp   = (const float*)d_in[13];
    const float* Wout  = (const float*)d_in[14];
    const float* bout  = (const float*)d_in[15];
    const float* gout  = (const float*)d_in[16];
    const float* beo   = (const float*)d_in[17];
    const float* Wf1   = (const float*)d_in[18];
    const float* bf1   = (const float*)d_in[19];
    const float* Wf2   = (const float*)d_in[20];
    const float* bf2   = (const float*)d_in[21];
    const float* gln   = (const float*)d_in[22];
    const float* bln   = (const float*)d_in[23];
    const float* Wpred = (const float*)d_in[24];
    const float* bpred = (const float*)d_in[25];

    float* ws     = (float*)d_ws;
    ushort_t* Qw  = (ushort_t*)d_ws;          // bf16 Q at offset 0
    float* imfT   = ws + OFF_IMFT;
    float* cpart0 = ws + OFF_CPART0;
    float* cpart1 = ws + OFF_CPART1;
    float* att    = ws + OFF_CPART0;          // alias: cpart dead after last red
    float* WiT    = ws + OFF_CPART0;          // alias: dead once ipot writes cpart0
    float* pcls   = ws + OFF_PCLS;
    float* icls   = ws + OFF_ICLS;
    float* bvec   = ws + OFF_BVEC;
    float* avec   = ws + OFF_AVEC;
    uint_t* flag  = (uint_t*)(ws + OFF_FLAG);
    float* WoutT  = ws + OFF_WOUTT;
    float* Wf1T   = ws + OFF_WF1T;
    float* Wf2T   = ws + OFF_WF2T;
    // post-att_gemm residents of the dead Q region:
    float* pf     = ws + 0u;                  // [2][2048][256]
    float* yb     = ws + 1048576u;            // [2][2048][256]
    float* y2     = ws + 2097152u;            // [2][2048][256]
    float* WpT    = ws + 3145728u;            // [256][256]

    float* out0 = (float*)d_out;                     // x       [2,256,2048]
    float* out1 = out0 + (size_t)2 * CH * N2;        // new_pos [2,2048,2]
    float* out2 = out1 + (size_t)2 * N2 * 2;         // center  [2,2,2048]

    // prologue (img side + weight transposes in persistent regions)
    cls_max_k<<<16, 256, 0, stream>>>(pcin, icin, pcls, icls);
    transpose_k<<<64, 256, 0, stream>>>(Wi, WiT, 256, 256);
    proj_rows<<<512, 256, 0, stream>>>(imgf, WiT, bi, Wkp, bkp, ipos, imfT);
    transpose_k<<<128, 256, 0, stream>>>(Wout, WoutT, 256, 512);
    transpose_k<<<256, 256, 0, stream>>>(Wf1, Wf1T, 1024, 256);
    transpose_k<<<256, 256, 0, stream>>>(Wf2, Wf2T, 256, 1024);

    // IPOT: 100 iterations, ONE kernel per iteration (fused reduce), bf16 Q
    // P_t (partials for b_t) lives in buf[t&1]; init writes P_1 -> cpart1.
    ipot_init_k<<<1024, 256, 0, stream>>>(Qw, ppos, ipos, pcls, avec, cpart1, flag);
    for (int t = 1; t < 100; ++t) {
        float* cR = (t & 1) ? cpart1 : cpart0;
        float* cW = (t & 1) ? cpart0 : cpart1;
        ipot_ur_k<<<1024, 256, 0, stream>>>(Qw, ppos, ipos, pcls, icls, avec,
                                            cR, cW, bvec, flag, t);
    }
    ipot_red_k<<<64, 256, 0, stream>>>(cpart0, icls, bvec);   // P_100 in buf[0]
    ipot_fin_k<<<1024, 256, 0, stream>>>(Qw, pcls, bvec, avec);

    // attention GEMM (K-split x4, atomic accumulate, bf16 R)
    att_zero_k<<<1024, 256, 0, stream>>>(att);
    att_gemm<<<1024, 256, 0, stream>>>(Qw, imfT, att);

    // pts projection (deferred; Q region now dead) + epilogue
    transpose_k<<<64, 256, 0, stream>>>(Wp, WpT, 256, 256);
    proj_rows<<<512, 256, 0, stream>>>(ptsf, WpT, bp, Wqp, bqp, ppos, pf);
    outproj_k<<<512, 256, 0, stream>>>(pf, att, WoutT, bout, gout, beo, yb);
    ffn_k<<<512, 256, 0, stream>>>(yb, Wf1T, bf1, Wf2T, bf2, gln, bln,
                                   Wpred, bpred, ppos, y2, out1, out2);
    out_x_k<<<1024, 256, 0, stream>>>(y2, out0);
}